// Round 9
// baseline (471.740 us; speedup 1.0000x reference)
//
#include <hip/hip_runtime.h>
#include <hip/hip_bf16.h>
#include <math.h>

#define N_NODES 50000
#define N_EDGES 600000
#define DIM 128
#define N_REL 8
#define N_GRAPHS 256
#define NBN 32                // nodes per block (grid 1563; last block half-full)
#define NBLK ((N_NODES + NBN - 1) / NBN)  // 1563
#define KDIM (N_REL * DIM)    // relation-stacked K = 1024
#define NKEY2 200064          // (NBLK*NBN)*4 pair-keys (covers tail nodes)
#define CAP 32                // bucket capacity (ints); max observed degree ~13-16

typedef __attribute__((ext_vector_type(8))) short short8;
typedef __attribute__((ext_vector_type(4))) float floatx4;
typedef __attribute__((ext_vector_type(4))) float f32x4;
typedef unsigned int uint;
typedef unsigned short ushort;

// ============================================================================
// SESSION CONCLUSIONS (R0-R8):
//  - k_layer is LATENCY-bound at the wave-occupancy ceiling: 32 waves/CU
//    (4 x 512-thread blocks), VALU ~21%, MFMA ~15%, HBM ~22%.
//  - ILP widening that keeps extra VGPRs live ACROSS phase 2 (R1/R3/R5/R6)
//    spills at (512,8): phase 2's live set (~60 of 64) has zero headroom.
//    Spill signature: WRITE_SIZE jumps 28 MB -> 44-190 MB.
//  - Relaxing to (512,6) (R7): no spill but 4->3 blocks/CU costs ~15%.
//  - R2 (split per-rel loops): slower — doubled latency exposures.
//  - R4 win: computed CAP-bucket bases deleted 4 aux dispatches. 461->435 us.
//  - R9 (this round): INTRA-phase-1 pipeline — hoist visit B's count+quad
//    load to phase-1 entry so it hides under visit A's gathers; loads die
//    before the barrier => the spill mechanism cannot fire by construction.
// ============================================================================

static __device__ __forceinline__ int lower_bound_i(const int* a, int n, int v) {
    int lo = 0, hi = n;
    while (lo < hi) { int mid = (lo + hi) >> 1; if (a[mid] < v) lo = mid + 1; else hi = mid; }
    return lo;
}

// scatter edges into fixed-CAP (dst, rel-pair) buckets; cursor doubles as counts.
// word = src(16b) | rel-parity(1b @16). CAP clamp: drop overflow (never fires
// for this dataset: Poisson λ=3 over 200K keys -> max ~16 << 32).
__global__ void k_fill(const int* __restrict__ src, const int* __restrict__ dst,
                       const int* __restrict__ etype, int* cursor,
                       int* __restrict__ edges, int e) {
    int i = blockIdx.x * blockDim.x + threadIdx.x;
    if (i < e) {
        const int et = etype[i];
        const int key = dst[i] * 4 + (et >> 1);
        int pos = atomicAdd(&cursor[key], 1);
        if (pos < CAP) edges[key * CAP + pos] = src[i] | ((et & 1) << 16);
    }
}

// W[k=r*128+dk][col] = sum_b comp[r,b]*bases[b][dk][col], packed bf16 hi/lo into
// MFMA-B-fragment order [kt:32][col:128][kk:32] ushort. All 3 layers, 1 launch.
// Also zeroes the CSR counts array (runs before k_fill on the stream) — saves
// the hipMemsetAsync dispatch.
__global__ void k_packW3(const float* __restrict__ b1, const float* __restrict__ c1,
                         ushort* __restrict__ Whi1, ushort* __restrict__ Wlo1,
                         const float* __restrict__ b2, const float* __restrict__ c2,
                         ushort* __restrict__ Whi2, ushort* __restrict__ Wlo2,
                         const float* __restrict__ b3, const float* __restrict__ c3,
                         ushort* __restrict__ Whi3, ushort* __restrict__ Wlo3,
                         int* __restrict__ cz) {
    const int gid = blockIdx.x * blockDim.x + threadIdx.x;  // 0..393215
    if (gid < NKEY2) cz[gid] = 0;
    const int lay = blockIdx.x >> 9;  // 512 blocks per layer
    const int id = (blockIdx.x & 511) * blockDim.x + threadIdx.x;  // 0..131071
    const float* bases = (lay == 0) ? b1 : (lay == 1) ? b2 : b3;
    const float* comp  = (lay == 0) ? c1 : (lay == 1) ? c2 : c3;
    ushort* Whi = (lay == 0) ? Whi1 : (lay == 1) ? Whi2 : Whi3;
    ushort* Wlo = (lay == 0) ? Wlo1 : (lay == 1) ? Wlo2 : Wlo3;
    int nn = id & 127, k = id >> 7;
    int r = k >> 7, dk = k & 127;
    const float* cp = comp + r * 8;
    float v = 0.f;
#pragma unroll
    for (int b = 0; b < 8; b++) v = fmaf(cp[b], bases[((size_t)b * 128 + dk) * 128 + nn], v);
    uint u = __float_as_uint(v);
    uint hu = (u + 0x7FFFu + ((u >> 16) & 1u)) & 0xFFFF0000u;
    float rf = v - __uint_as_float(hu);
    uint ur = __float_as_uint(rf);
    uint lu = (ur + 0x7FFFu + ((ur >> 16) & 1u)) >> 16;
    int kt = k >> 5, kk = k & 31;
    int off = kt * 4096 + nn * 32 + kk;
    Whi[off] = (ushort)(hu >> 16);
    Wlo[off] = (ushort)lu;
}

// One RGCN layer, fused, 512 threads (8 waves), 32 nodes/block, FOUR K-rounds
// (one relation PAIR per round, 33 KB LDS -> 4 blocks/CU = the 32-wave cap).
// R4 CAP-bucket structure + R9 intra-phase-1 pipeline:
//   Both visits' counts + first edge quads are loaded AT PHASE-1 ENTRY
//   (computed addresses). Visit B's quad load hides under visit A's gather
//   latency; by flush-A, B's words have arrived and B's gathers issue
//   immediately. All pipeline registers DIE before the barrier — nothing
//   extra is live across phase 2, so the R1/R3/R5/R6 spill mechanism cannot
//   fire. Live-set peak in phase 1: ~48 VGPR < 64.
//   Garbage safety: index clamp min(w&0xFFFF, N_NODES-1) has NO cnt
//   dependency (gathers never wait on cnt); accumulate masked by rem>k;
//   cnt clamped to CAP; tail-node buckets have cnt 0. Parity bit (bit16)
//   selects even/odd rel accumulator (free under latency — R2 lesson).
//   Flush: v_cvt_pk_bf16_f32 + exact residual. LDS slot math: 0 bank confl.
//   phase 2: MFMA kt ro*8..ro*8+7 accumulating into persistent VGPRs;
//   B (relation-stacked W, comp folded) read once per 32 nodes.
//  GATE (layer 3): epilogue via 16-lane shuffle reduce + LDS partials (NO
//  ATOMICS — prev-session R7 pitfall).
//
// PITFALL (prev session R3): do NOT scalarize loads of per-call-rebuilt
// arrays (edges/counts) — compiler s_load via scalar cache serves STALE data
// on graph replay. Keep lane-derived (vector) addressing.
// PITFALL (prev session R7): NO per-lane float atomicAdd on LDS — CAS loop.
// PITFALL (R1/R3/R5/R6): ANY extra VGPRs live across phase 2 at (512,8)
// spill. R7: (512,6) loses a resident block, -15%.
// Tripwire: WRITE_SIZE >> 28126 KB means spill -> revert to R8.
template <bool RELU, bool GATE>
__global__ __launch_bounds__(512, 8) void k_layer(
    const float* __restrict__ xin, float* __restrict__ hout,
    const int* __restrict__ edges, const int* __restrict__ counts,
    const ushort* __restrict__ Whi, const ushort* __restrict__ Wlo,
    const float* __restrict__ bias,
    const float* __restrict__ gw, const float* __restrict__ gb,
    float* __restrict__ gate) {
    __shared__ ushort sHi[8 * 1024];  // 16 KiB: [ktp:8][chunk:128][8]
    __shared__ ushort sLo[8 * 1024];  // 16 KiB
    __shared__ float sgatep[NBN][8];
    const int tid = threadIdx.x;
    const int lane = tid & 63;
    const int w = tid >> 6;
    const int q2 = lane >> 4, mm = lane & 15;
    const int xev = (mm ^ q2) * 8;        // A chunk sub-offset, kt even
    const int xod = ((mm ^ q2) ^ 4) * 8;  // kt odd (parity swizzle)
    const int aq = q2 * 256;              // q-group base (ushort)
    const int n0 = w * 16 + mm;
    const ushort* bph = Whi + n0 * 32 + q2 * 8;
    const ushort* bpl = Wlo + n0 * 32 + q2 * 8;
    floatx4 acc0 = {0.f, 0.f, 0.f, 0.f};  // rows 0..15
    floatx4 acc1 = {0.f, 0.f, 0.f, 0.f};  // rows 16..31

    const int hw = tid >> 5, l5 = tid & 31;
    const int d0 = l5 * 4;
    const int kt_off = l5 >> 3;      // 0..3
    const int q = (l5 >> 1) & 3;
    const int jb = (l5 & 1) * 4;
    const float* xl = xin + d0;      // lane-local column base
    const int mA = hw * 2, mB = mA + 1;
    const int nA = blockIdx.x * NBN + mA;
    const int nB = nA + 1;

    auto flushv = [&](const f32x4& a, int u) {
        uint h0, h1, l0, l1;
        asm("v_cvt_pk_bf16_f32 %0, %1, %2" : "=v"(h0) : "v"(a.x), "v"(a.y));
        asm("v_cvt_pk_bf16_f32 %0, %1, %2" : "=v"(h1) : "v"(a.z), "v"(a.w));
        const float rx = a.x - __uint_as_float(h0 << 16);
        const float ry = a.y - __uint_as_float(h0 & 0xFFFF0000u);
        const float rz = a.z - __uint_as_float(h1 << 16);
        const float rw = a.w - __uint_as_float(h1 & 0xFFFF0000u);
        asm("v_cvt_pk_bf16_f32 %0, %1, %2" : "=v"(l0) : "v"(rx), "v"(ry));
        asm("v_cvt_pk_bf16_f32 %0, %1, %2" : "=v"(l1) : "v"(rz), "v"(rw));
        *(uint2*)(sHi + u) = make_uint2(h0, h1);
        *(uint2*)(sLo + u) = make_uint2(l0, l1);
    };

    // masked quad-accumulate: gathers issue with no cnt dependency (clamp only)
    auto gatherquad = [&](const int4& qw, int rem, f32x4& a0, f32x4& a1) {
        const int i0 = min(qw.x & 0xFFFF, N_NODES - 1);
        const int i1 = min(qw.y & 0xFFFF, N_NODES - 1);
        const int i2 = min(qw.z & 0xFFFF, N_NODES - 1);
        const int i3 = min(qw.w & 0xFFFF, N_NODES - 1);
        const f32x4 v0 = *(const f32x4*)(xl + ((size_t)i0 << 7));
        const f32x4 v1 = *(const f32x4*)(xl + ((size_t)i1 << 7));
        const f32x4 v2 = *(const f32x4*)(xl + ((size_t)i2 << 7));
        const f32x4 v3 = *(const f32x4*)(xl + ((size_t)i3 << 7));
        if (rem > 0) { if (qw.x & 0x10000) a1 += v0; else a0 += v0; }
        if (rem > 1) { if (qw.y & 0x10000) a1 += v1; else a0 += v1; }
        if (rem > 2) { if (qw.z & 0x10000) a1 += v2; else a0 += v2; }
        if (rem > 3) { if (qw.w & 0x10000) a1 += v3; else a0 += v3; }
    };

    for (int ro = 0; ro < 4; ++ro) {
        // ---- phase 1 entry: issue BOTH visits' counts + first quads NOW ----
        // (computed addresses; qB's ~500cy latency hides under visit A's
        //  gathers; all four values are dead before the barrier)
        const int keyA = nA * 4 + ro;
        const int keyB = nB * 4 + ro;
        int cA = 0, cB = 0;
        if (nA < N_NODES) cA = counts[keyA];
        if (nB < N_NODES) cB = counts[keyB];
        const int4 qA = *(const int4*)(edges + keyA * CAP);
        const int4 qB = *(const int4*)(edges + keyB * CAP);
        cA = min(cA, CAP);
        cB = min(cB, CAP);

        {   // ---- visit A (node nA, row mA) ----
            f32x4 a0 = (f32x4)0.f, a1 = (f32x4)0.f;
            gatherquad(qA, cA, a0, a1);
            if (cA > 4) {  // slow path: ~19% of buckets (uniform per half-wave)
                int e = keyA * CAP + 4;
                int r2 = cA - 4;
                do {
                    const int4 q2v = *(const int4*)(edges + e);
                    gatherquad(q2v, r2, a0, a1);
                    e += 4; r2 -= 4;
                } while (r2 > 0);
            }
            const int ktp0 = kt_off;                 // even rel -> ktp 0..3
            const int ch0 = q * 32 + ((mA ^ q) ^ ((ktp0 & 1) << 2));
            flushv(a0, ktp0 * 1024 + ch0 * 8 + jb);
            const int ktp1 = 4 + kt_off;             // odd rel -> ktp 4..7
            const int ch1 = q * 32 + ((mA ^ q) ^ ((ktp1 & 1) << 2));
            flushv(a1, ktp1 * 1024 + ch1 * 8 + jb);
        }
        {   // ---- visit B (node nB, row mB): quad already in flight ----
            f32x4 a0 = (f32x4)0.f, a1 = (f32x4)0.f;
            gatherquad(qB, cB, a0, a1);
            if (cB > 4) {
                int e = keyB * CAP + 4;
                int r2 = cB - 4;
                do {
                    const int4 q2v = *(const int4*)(edges + e);
                    gatherquad(q2v, r2, a0, a1);
                    e += 4; r2 -= 4;
                } while (r2 > 0);
            }
            const int ktp0 = kt_off;
            const int ch0 = q * 32 + ((mB ^ q) ^ ((ktp0 & 1) << 2));
            flushv(a0, ktp0 * 1024 + ch0 * 8 + jb);
            const int ktp1 = 4 + kt_off;
            const int ch1 = q * 32 + ((mB ^ q) ^ ((ktp1 & 1) << 2));
            flushv(a1, ktp1 * 1024 + ch1 * 8 + jb);
        }
        __syncthreads();

        // ---- phase 2 (this K-quarter): MFMA, wave owns 16-col strip, 2 row-tiles ----
        for (int kt = 0; kt < 8; kt += 2) {
            {
                const int ktg = ro * 8 + kt;
                const ushort* ap = sHi + kt * 1024 + aq;
                const ushort* alp = sLo + kt * 1024 + aq;
                const short8 ah0 = *(const short8*)(ap + xev);
                const short8 ah1 = *(const short8*)(ap + 128 + xev);
                const short8 al0 = *(const short8*)(alp + xev);
                const short8 al1 = *(const short8*)(alp + 128 + xev);
                const short8 bh = *(const short8*)(bph + ktg * 4096);
                const short8 bl = *(const short8*)(bpl + ktg * 4096);
                acc0 = __builtin_amdgcn_mfma_f32_16x16x32_bf16(ah0, bh, acc0, 0, 0, 0);
                acc1 = __builtin_amdgcn_mfma_f32_16x16x32_bf16(ah1, bh, acc1, 0, 0, 0);
                acc0 = __builtin_amdgcn_mfma_f32_16x16x32_bf16(ah0, bl, acc0, 0, 0, 0);
                acc1 = __builtin_amdgcn_mfma_f32_16x16x32_bf16(ah1, bl, acc1, 0, 0, 0);
                acc0 = __builtin_amdgcn_mfma_f32_16x16x32_bf16(al0, bh, acc0, 0, 0, 0);
                acc1 = __builtin_amdgcn_mfma_f32_16x16x32_bf16(al1, bh, acc1, 0, 0, 0);
            }
            {
                const int kto = kt + 1;
                const int ktg = ro * 8 + kto;
                const ushort* ap = sHi + kto * 1024 + aq;
                const ushort* alp = sLo + kto * 1024 + aq;
                const short8 ah0 = *(const short8*)(ap + xod);
                const short8 ah1 = *(const short8*)(ap + 128 + xod);
                const short8 al0 = *(const short8*)(alp + xod);
                const short8 al1 = *(const short8*)(alp + 128 + xod);
                const short8 bh = *(const short8*)(bph + ktg * 4096);
                const short8 bl = *(const short8*)(bpl + ktg * 4096);
                acc0 = __builtin_amdgcn_mfma_f32_16x16x32_bf16(ah0, bh, acc0, 0, 0, 0);
                acc1 = __builtin_amdgcn_mfma_f32_16x16x32_bf16(ah1, bh, acc1, 0, 0, 0);
                acc0 = __builtin_amdgcn_mfma_f32_16x16x32_bf16(ah0, bl, acc0, 0, 0, 0);
                acc1 = __builtin_amdgcn_mfma_f32_16x16x32_bf16(ah1, bl, acc1, 0, 0, 0);
                acc0 = __builtin_amdgcn_mfma_f32_16x16x32_bf16(al0, bh, acc0, 0, 0, 0);
                acc1 = __builtin_amdgcn_mfma_f32_16x16x32_bf16(al1, bh, acc1, 0, 0, 0);
            }
        }
        if (ro < 3) __syncthreads();  // phase-2 reads done before next round's flush
    }

    // ---- epilogue: bias/relu, store, optional fused gate ----
    const float b0 = bias[n0];
    float gp0[4], gp1[4];
#pragma unroll
    for (int r = 0; r < 4; r++) {
        const int row0 = q2 * 4 + r;            // C/D: row=(lane>>4)*4+reg, col=lane&15
        const int nodeA = blockIdx.x * NBN + row0;
        const int nodeB = nodeA + 16;
        float v0 = acc0[r] + b0;
        float v1 = acc1[r] + b0;
        if (RELU) { v0 = fmaxf(v0, 0.f); v1 = fmaxf(v1, 0.f); }
        if (nodeA < N_NODES) hout[(size_t)nodeA * DIM + n0] = v0;
        if (nodeB < N_NODES) hout[(size_t)nodeB * DIM + n0] = v1;
        if (GATE) { gp0[r] = v0 * gw[n0]; gp1[r] = v1 * gw[n0]; }
    }
    if (GATE) {
#pragma unroll
        for (int r = 0; r < 4; r++) {
#pragma unroll
            for (int s = 1; s < 16; s <<= 1) {
                gp0[r] += __shfl_xor(gp0[r], s, 16);
                gp1[r] += __shfl_xor(gp1[r], s, 16);
            }
        }
        __syncthreads();  // all phase-2 LDS reads done (paranoia; sgatep separate)
        if (mm == 0) {
#pragma unroll
            for (int r = 0; r < 4; r++) {
                sgatep[q2 * 4 + r][w] = gp0[r];
                sgatep[16 + q2 * 4 + r][w] = gp1[r];
            }
        }
        __syncthreads();
        if (tid < NBN) {
            const int n = blockIdx.x * NBN + tid;
            if (n < N_NODES) {
                float s = 0.f;
#pragma unroll
                for (int w8 = 0; w8 < 8; w8++) s += sgatep[tid][w8];
                gate[n] = s + gb[0];
            }
        }
    }
}

// One block (256 threads) per graph: segment softmax + weighted readout + MLP head + sigmoid.
__global__ __launch_bounds__(256) void k_pool(
    const float* __restrict__ h3, const float* __restrict__ gate, const int* __restrict__ n2g,
    const float* __restrict__ fc1w, const float* __restrict__ fc1b,
    const float* __restrict__ fc2w, const float* __restrict__ fc2b,
    const float* __restrict__ fc3w, const float* __restrict__ fc3b,
    float* __restrict__ out, int N) {
    const int g = blockIdx.x;
    const int tid = threadIdx.x;
    __shared__ float sred[256];
    __shared__ float sr[128];
    __shared__ float sz1[100];
    __shared__ float sz2[64];
    __shared__ float sm, ssum;

    const int s = lower_bound_i(n2g, N, g);
    const int e = lower_bound_i(n2g, N, g + 1);

    float m = -3.4e38f;
    for (int n = s + tid; n < e; n += 256) m = fmaxf(m, gate[n]);
    sred[tid] = m;
    __syncthreads();
    for (int off = 128; off > 0; off >>= 1) {
        if (tid < off) sred[tid] = fmaxf(sred[tid], sred[tid + off]);
        __syncthreads();
    }
    if (tid == 0) sm = sred[0];
    __syncthreads();
    const float mm = sm;

    float sum = 0.f;
    for (int n = s + tid; n < e; n += 256) sum += expf(gate[n] - mm);
    sred[tid] = sum;
    __syncthreads();
    for (int off = 128; off > 0; off >>= 1) {
        if (tid < off) sred[tid] += sred[tid + off];
        __syncthreads();
    }
    if (tid == 0) ssum = sred[0];
    __syncthreads();
    const float inv = (e > s) ? 1.0f / ssum : 0.f;

    // weighted readout: col = tid&127, node stream split across two halves,
    // unrolled x4 per half (8 loads in flight across the block)
    const int col = tid & 127;
    const int half = tid >> 7;
    float acc = 0.f;
    int n = s + half;
    for (; n + 6 < e; n += 8) {
        const float w0 = expf(gate[n] - mm);
        const float w1 = expf(gate[n + 2] - mm);
        const float w2 = expf(gate[n + 4] - mm);
        const float w3 = expf(gate[n + 6] - mm);
        const float a0 = h3[(size_t)n * DIM + col];
        const float a1 = h3[(size_t)(n + 2) * DIM + col];
        const float a2 = h3[(size_t)(n + 4) * DIM + col];
        const float a3 = h3[(size_t)(n + 6) * DIM + col];
        acc = fmaf(w0, a0, acc);
        acc = fmaf(w1, a1, acc);
        acc = fmaf(w2, a2, acc);
        acc = fmaf(w3, a3, acc);
    }
    for (; n < e; n += 2) {
        const float wgt = expf(gate[n] - mm);
        acc = fmaf(wgt, h3[(size_t)n * DIM + col], acc);
    }
    sred[tid] = acc;
    __syncthreads();
    if (tid < 128) sr[tid] = (sred[tid] + sred[tid + 128]) * inv;
    __syncthreads();

    if (tid < 100) {
        float t = fc1b[tid];
        for (int i = 0; i < 128; i++) t = fmaf(sr[i], fc1w[i * 100 + tid], t);
        sz1[tid] = fmaxf(t, 0.f);
    }
    __syncthreads();
    if (tid < 64) {
        float t = fc2b[tid];
        for (int i = 0; i < 100; i++) t = fmaf(sz1[i], fc2w[i * 64 + tid], t);
        sz2[tid] = fmaxf(t, 0.f);
    }
    __syncthreads();
    if (tid < 64) {
        float p = sz2[tid] * fc3w[tid];
#pragma unroll
        for (int off = 32; off > 0; off >>= 1) p += __shfl_down(p, off, 64);
        if (tid == 0) {
            const float z = p + fc3b[0];
            out[g] = 1.0f / (1.0f + expf(-z));
        }
    }
}

extern "C" void kernel_launch(void* const* d_in, const int* in_sizes, int n_in,
                              void* d_out, int out_size, void* d_ws, size_t ws_size,
                              hipStream_t stream) {
    (void)in_sizes; (void)n_in; (void)out_size; (void)ws_size;
    const float* features = (const float*)d_in[0];
    const int*   src      = (const int*)d_in[1];
    const int*   dst      = (const int*)d_in[2];
    const int*   etype    = (const int*)d_in[3];
    const int*   n2g      = (const int*)d_in[4];
    const float* bases1   = (const float*)d_in[5];
    const float* comp1    = (const float*)d_in[6];
    const float* bias1    = (const float*)d_in[7];
    const float* bases2   = (const float*)d_in[8];
    const float* comp2    = (const float*)d_in[9];
    const float* bias2    = (const float*)d_in[10];
    const float* bases3   = (const float*)d_in[11];
    const float* comp3    = (const float*)d_in[12];
    const float* bias3    = (const float*)d_in[13];
    const float* gate_w   = (const float*)d_in[14];
    const float* gate_b   = (const float*)d_in[15];
    const float* fc1w     = (const float*)d_in[16];
    const float* fc1b     = (const float*)d_in[17];
    const float* fc2w     = (const float*)d_in[18];
    const float* fc2b     = (const float*)d_in[19];
    const float* fc3w     = (const float*)d_in[20];
    const float* fc3b     = (const float*)d_in[21];
    float* out = (float*)d_out;

    char* w = (char*)d_ws;
    auto alloc = [&](size_t bytes) -> char* {
        char* p = w;
        w += (bytes + 255) & ~(size_t)255;
        return p;
    };
    int*    counts  = (int*)alloc((NKEY2 + 64) * sizeof(int));            // 0.8 MB
    int*    edges   = (int*)alloc(((size_t)NKEY2 * CAP + 64) * sizeof(int));  // 25.6 MB
    float*  hA      = (float*)alloc((size_t)N_NODES * DIM * sizeof(float));
    float*  hB      = (float*)alloc((size_t)N_NODES * DIM * sizeof(float));
    float*  gate    = (float*)alloc(N_NODES * sizeof(float));
    ushort* Whi1    = (ushort*)alloc((size_t)KDIM * DIM * sizeof(ushort));
    ushort* Wlo1    = (ushort*)alloc((size_t)KDIM * DIM * sizeof(ushort));
    ushort* Whi2    = (ushort*)alloc((size_t)KDIM * DIM * sizeof(ushort));
    ushort* Wlo2    = (ushort*)alloc((size_t)KDIM * DIM * sizeof(ushort));
    ushort* Whi3    = (ushort*)alloc((size_t)KDIM * DIM * sizeof(ushort));
    ushort* Wlo3    = (ushort*)alloc((size_t)KDIM * DIM * sizeof(ushort));

    // weight packing (+ counts zeroing, ordered before k_fill on the stream)
    k_packW3<<<1536, 256, 0, stream>>>(bases1, comp1, Whi1, Wlo1,
                                       bases2, comp2, Whi2, Wlo2,
                                       bases3, comp3, Whi3, Wlo3, counts);

    // CAP-bucket CSR (rebuilt every call): fill only (no memset/count/scan)
    k_fill<<<(N_EDGES + 255) / 256, 256, 0, stream>>>(src, dst, etype, counts, edges, N_EDGES);

    // 3 RGCN layers (bucketed aggregation + 4-round K-quartered MFMA GEMM)
    k_layer<true, false><<<NBLK, 512, 0, stream>>>(features, hA, edges, counts, Whi1, Wlo1, bias1, gate_w, gate_b, gate);
    k_layer<true, false><<<NBLK, 512, 0, stream>>>(hA, hB, edges, counts, Whi2, Wlo2, bias2, gate_w, gate_b, gate);
    k_layer<false, true><<<NBLK, 512, 0, stream>>>(hB, hA, edges, counts, Whi3, Wlo3, bias3, gate_w, gate_b, gate);

    // pooling + MLP head (gate computed in layer 3)
    k_pool<<<N_GRAPHS, 256, 0, stream>>>(hA, gate, n2g, fc1w, fc1b, fc2w, fc2b, fc3w, fc3b, out, N_NODES);
}

// Round 10
// 433.842 us; speedup vs baseline: 1.0874x; 1.0874x over previous
//
#include <hip/hip_runtime.h>
#include <hip/hip_bf16.h>
#include <math.h>

#define N_NODES 50000
#define N_EDGES 600000
#define DIM 128
#define N_REL 8
#define N_GRAPHS 256
#define NBN 32                // nodes per block (grid 1563; last block half-full)
#define NBLK ((N_NODES + NBN - 1) / NBN)  // 1563
#define KDIM (N_REL * DIM)    // relation-stacked K = 1024
#define NKEY2 200064          // (NBLK*NBN)*4 pair-keys (covers tail nodes)
#define CAP 32                // bucket capacity (ints); max observed degree ~13-16

typedef __attribute__((ext_vector_type(8))) short short8;
typedef __attribute__((ext_vector_type(4))) float floatx4;
typedef __attribute__((ext_vector_type(4))) float f32x4;
typedef unsigned int uint;
typedef unsigned short ushort;

// ============================================================================
// FINAL SESSION CONCLUSIONS (R0-R9) — the exploration map is complete:
//  - k_layer is LATENCY-bound at the wave-occupancy ceiling: 32 waves/CU
//    (4 x 512-thread blocks), VALU ~21%, MFMA ~15%, HBM ~22%. No pipe
//    saturated; the floor is serial gather-chain latency with max TLP.
//  - The VGPR budget at (512,8) is a WHOLE-KERNEL 64-reg allocation. The
//    peak live set ANYWHERE (phase 1 incl. persistent acc0/acc1, or phase 2)
//    determines allocation. This config sits exactly at the cliff:
//      * regs live across phase 2 (R1/R5/R6): spill
//      * regs live only within phase 1 (R3/R9): ALSO spill
//    Spill signature: WRITE_SIZE 28 MB -> 44-190 MB + SQ_LDS_BANK_CONFLICT
//    = 206312.
//  - Relaxing to (512,6) (R7): no spill, but 4->3 blocks/CU costs ~15% —
//    occupancy binds harder than any hidden latency. Do NOT relax bounds.
//  - R2 (split per-rel loops, fewer VALU): slower — doubled latency
//    exposures. Per-edge parity select is FREE under latency; keep it.
//  - The only durable win: R4's computed CAP-bucket bases deleted 4 aux
//    dispatches (count + 3-kernel scan) + big memset. 461 -> 435.4 us
//    (re-verified R8). THIS FILE IS THAT CONFIGURATION.
//  - Untried ideas are structural rewrites (de-fused aggregate/GEMM with
//    ~200 MB/layer extra HBM traffic; bf16 feature storage with numerics
//    risk) — not neighborhood moves.
// ============================================================================

static __device__ __forceinline__ int lower_bound_i(const int* a, int n, int v) {
    int lo = 0, hi = n;
    while (lo < hi) { int mid = (lo + hi) >> 1; if (a[mid] < v) lo = mid + 1; else hi = mid; }
    return lo;
}

// scatter edges into fixed-CAP (dst, rel-pair) buckets; cursor doubles as counts.
// word = src(16b) | rel-parity(1b @16). CAP clamp: drop overflow (never fires
// for this dataset: Poisson λ=3 over 200K keys -> max ~16 << 32).
__global__ void k_fill(const int* __restrict__ src, const int* __restrict__ dst,
                       const int* __restrict__ etype, int* cursor,
                       int* __restrict__ edges, int e) {
    int i = blockIdx.x * blockDim.x + threadIdx.x;
    if (i < e) {
        const int et = etype[i];
        const int key = dst[i] * 4 + (et >> 1);
        int pos = atomicAdd(&cursor[key], 1);
        if (pos < CAP) edges[key * CAP + pos] = src[i] | ((et & 1) << 16);
    }
}

// W[k=r*128+dk][col] = sum_b comp[r,b]*bases[b][dk][col], packed bf16 hi/lo into
// MFMA-B-fragment order [kt:32][col:128][kk:32] ushort. All 3 layers, 1 launch.
// Also zeroes the CSR counts array (runs before k_fill on the stream) — saves
// the hipMemsetAsync dispatch.
__global__ void k_packW3(const float* __restrict__ b1, const float* __restrict__ c1,
                         ushort* __restrict__ Whi1, ushort* __restrict__ Wlo1,
                         const float* __restrict__ b2, const float* __restrict__ c2,
                         ushort* __restrict__ Whi2, ushort* __restrict__ Wlo2,
                         const float* __restrict__ b3, const float* __restrict__ c3,
                         ushort* __restrict__ Whi3, ushort* __restrict__ Wlo3,
                         int* __restrict__ cz) {
    const int gid = blockIdx.x * blockDim.x + threadIdx.x;  // 0..393215
    if (gid < NKEY2) cz[gid] = 0;
    const int lay = blockIdx.x >> 9;  // 512 blocks per layer
    const int id = (blockIdx.x & 511) * blockDim.x + threadIdx.x;  // 0..131071
    const float* bases = (lay == 0) ? b1 : (lay == 1) ? b2 : b3;
    const float* comp  = (lay == 0) ? c1 : (lay == 1) ? c2 : c3;
    ushort* Whi = (lay == 0) ? Whi1 : (lay == 1) ? Whi2 : Whi3;
    ushort* Wlo = (lay == 0) ? Wlo1 : (lay == 1) ? Wlo2 : Wlo3;
    int nn = id & 127, k = id >> 7;
    int r = k >> 7, dk = k & 127;
    const float* cp = comp + r * 8;
    float v = 0.f;
#pragma unroll
    for (int b = 0; b < 8; b++) v = fmaf(cp[b], bases[((size_t)b * 128 + dk) * 128 + nn], v);
    uint u = __float_as_uint(v);
    uint hu = (u + 0x7FFFu + ((u >> 16) & 1u)) & 0xFFFF0000u;
    float rf = v - __uint_as_float(hu);
    uint ur = __float_as_uint(rf);
    uint lu = (ur + 0x7FFFu + ((ur >> 16) & 1u)) >> 16;
    int kt = k >> 5, kk = k & 31;
    int off = kt * 4096 + nn * 32 + kk;
    Whi[off] = (ushort)(hu >> 16);
    Wlo[off] = (ushort)lu;
}

// One RGCN layer, fused, 512 threads (8 waves), 32 nodes/block, FOUR K-rounds
// (one relation PAIR per round, 33 KB LDS -> 4 blocks/CU = the 32-wave cap).
// R4 configuration — verified best (435.4 us total, k_layer ~103 us, R8).
//   CAP-bucket CSR: bucket base b0 = key*CAP is COMPUTED (no scan/offsets
//   load); edge-quad load issues immediately; count load (L2-hot) runs in
//   parallel and is consumed only by masks/loop bound.
//   Garbage safety: index clamp min(w&0xFFFF, N_NODES-1) has NO cnt
//   dependency (gathers never wait on cnt); accumulate masked by rem>k;
//   cnt clamped to CAP; tail-node buckets have cnt 0. Parity bit (bit16)
//   selects even/odd rel accumulator (free under latency — R2 lesson).
//   Flush: v_cvt_pk_bf16_f32 + exact residual (lo = x - hi_as_f32, correct
//   for any cvt rounding mode). LDS slot math (ktp/ch/jb swizzle): 0 bank
//   conflicts.
//   phase 2: MFMA kt ro*8..ro*8+7 accumulating into persistent VGPRs;
//   B (relation-stacked W, comp folded) read once per 32 nodes.
//  GATE (layer 3): epilogue via 16-lane shuffle reduce + LDS partials (NO
//  ATOMICS — prev-session R7 pitfall).
//
// PITFALL (prev session R3): do NOT scalarize loads of per-call-rebuilt
// arrays (edges/counts) — compiler s_load via scalar cache serves STALE data
// on graph replay. Keep lane-derived (vector) addressing.
// PITFALL (prev session R7): NO per-lane float atomicAdd on LDS — CAS loop.
// PITFALL (R1/R3/R5/R6/R9): ANY extra VGPRs ANYWHERE (not just across the
// barrier) at (512,8) spill. R7: (512,6) loses a resident block, -15%.
// DO NOT MODIFY phase 1 or phase 2 register usage without checking
// WRITE_SIZE == ~28126 KB stays true.
template <bool RELU, bool GATE>
__global__ __launch_bounds__(512, 8) void k_layer(
    const float* __restrict__ xin, float* __restrict__ hout,
    const int* __restrict__ edges, const int* __restrict__ counts,
    const ushort* __restrict__ Whi, const ushort* __restrict__ Wlo,
    const float* __restrict__ bias,
    const float* __restrict__ gw, const float* __restrict__ gb,
    float* __restrict__ gate) {
    __shared__ ushort sHi[8 * 1024];  // 16 KiB: [ktp:8][chunk:128][8]
    __shared__ ushort sLo[8 * 1024];  // 16 KiB
    __shared__ float sgatep[NBN][8];
    const int tid = threadIdx.x;
    const int lane = tid & 63;
    const int w = tid >> 6;
    const int q2 = lane >> 4, mm = lane & 15;
    const int xev = (mm ^ q2) * 8;        // A chunk sub-offset, kt even
    const int xod = ((mm ^ q2) ^ 4) * 8;  // kt odd (parity swizzle)
    const int aq = q2 * 256;              // q-group base (ushort)
    const int n0 = w * 16 + mm;
    const ushort* bph = Whi + n0 * 32 + q2 * 8;
    const ushort* bpl = Wlo + n0 * 32 + q2 * 8;
    floatx4 acc0 = {0.f, 0.f, 0.f, 0.f};  // rows 0..15
    floatx4 acc1 = {0.f, 0.f, 0.f, 0.f};  // rows 16..31

    const int hw = tid >> 5, l5 = tid & 31;
    const int d0 = l5 * 4;
    const int kt_off = l5 >> 3;      // 0..3
    const int q = (l5 >> 1) & 3;
    const int jb = (l5 & 1) * 4;
    const float* xl = xin + d0;      // lane-local column base

    auto flushv = [&](const f32x4& a, int u) {
        uint h0, h1, l0, l1;
        asm("v_cvt_pk_bf16_f32 %0, %1, %2" : "=v"(h0) : "v"(a.x), "v"(a.y));
        asm("v_cvt_pk_bf16_f32 %0, %1, %2" : "=v"(h1) : "v"(a.z), "v"(a.w));
        const float rx = a.x - __uint_as_float(h0 << 16);
        const float ry = a.y - __uint_as_float(h0 & 0xFFFF0000u);
        const float rz = a.z - __uint_as_float(h1 << 16);
        const float rw = a.w - __uint_as_float(h1 & 0xFFFF0000u);
        asm("v_cvt_pk_bf16_f32 %0, %1, %2" : "=v"(l0) : "v"(rx), "v"(ry));
        asm("v_cvt_pk_bf16_f32 %0, %1, %2" : "=v"(l1) : "v"(rz), "v"(rw));
        *(uint2*)(sHi + u) = make_uint2(h0, h1);
        *(uint2*)(sLo + u) = make_uint2(l0, l1);
    };

    for (int ro = 0; ro < 4; ++ro) {
        // ---- phase 1: aggregate rel pair {2ro,2ro+1}; 2 nodes per half-wave ----
        for (int v = 0; v < 2; ++v) {
            const int m = hw * 2 + v;
            const int n = blockIdx.x * NBN + m;
            const int key = n * 4 + ro;
            int cnt = 0;
            if (n < N_NODES) cnt = counts[key];   // issued ASAP; consumed late
            cnt = min(cnt, CAP);
            const int b0 = key * CAP;             // COMPUTED base: no offsets load
            f32x4 a0 = (f32x4)0.f, a1 = (f32x4)0.f;
            int e = b0, rem = cnt;
            do {
                const int w0 = edges[e];
                const int w1 = edges[e + 1];
                const int w2 = edges[e + 2];
                const int w3 = edges[e + 3];
                // clamp: garbage-safe, NO cnt dependency -> gathers issue now
                const int i0 = min(w0 & 0xFFFF, N_NODES - 1);
                const int i1 = min(w1 & 0xFFFF, N_NODES - 1);
                const int i2 = min(w2 & 0xFFFF, N_NODES - 1);
                const int i3 = min(w3 & 0xFFFF, N_NODES - 1);
                const f32x4 v0 = *(const f32x4*)(xl + ((size_t)i0 << 7));
                const f32x4 v1 = *(const f32x4*)(xl + ((size_t)i1 << 7));
                const f32x4 v2 = *(const f32x4*)(xl + ((size_t)i2 << 7));
                const f32x4 v3 = *(const f32x4*)(xl + ((size_t)i3 << 7));
                if (rem > 0) { if (w0 & 0x10000) a1 += v0; else a0 += v0; }
                if (rem > 1) { if (w1 & 0x10000) a1 += v1; else a0 += v1; }
                if (rem > 2) { if (w2 & 0x10000) a1 += v2; else a0 += v2; }
                if (rem > 3) { if (w3 & 0x10000) a1 += v3; else a0 += v3; }
                e += 4; rem -= 4;
            } while (rem > 0);
            // unconditional flush of both rels (full slot coverage -> no zeroing)
            {
                const int ktp0 = kt_off;                 // even rel -> ktp 0..3
                const int ch0 = q * 32 + ((m ^ q) ^ ((ktp0 & 1) << 2));
                flushv(a0, ktp0 * 1024 + ch0 * 8 + jb);
                const int ktp1 = 4 + kt_off;             // odd rel -> ktp 4..7
                const int ch1 = q * 32 + ((m ^ q) ^ ((ktp1 & 1) << 2));
                flushv(a1, ktp1 * 1024 + ch1 * 8 + jb);
            }
        }
        __syncthreads();

        // ---- phase 2 (this K-quarter): MFMA, wave owns 16-col strip, 2 row-tiles ----
        for (int kt = 0; kt < 8; kt += 2) {
            {
                const int ktg = ro * 8 + kt;
                const ushort* ap = sHi + kt * 1024 + aq;
                const ushort* alp = sLo + kt * 1024 + aq;
                const short8 ah0 = *(const short8*)(ap + xev);
                const short8 ah1 = *(const short8*)(ap + 128 + xev);
                const short8 al0 = *(const short8*)(alp + xev);
                const short8 al1 = *(const short8*)(alp + 128 + xev);
                const short8 bh = *(const short8*)(bph + ktg * 4096);
                const short8 bl = *(const short8*)(bpl + ktg * 4096);
                acc0 = __builtin_amdgcn_mfma_f32_16x16x32_bf16(ah0, bh, acc0, 0, 0, 0);
                acc1 = __builtin_amdgcn_mfma_f32_16x16x32_bf16(ah1, bh, acc1, 0, 0, 0);
                acc0 = __builtin_amdgcn_mfma_f32_16x16x32_bf16(ah0, bl, acc0, 0, 0, 0);
                acc1 = __builtin_amdgcn_mfma_f32_16x16x32_bf16(ah1, bl, acc1, 0, 0, 0);
                acc0 = __builtin_amdgcn_mfma_f32_16x16x32_bf16(al0, bh, acc0, 0, 0, 0);
                acc1 = __builtin_amdgcn_mfma_f32_16x16x32_bf16(al1, bh, acc1, 0, 0, 0);
            }
            {
                const int kto = kt + 1;
                const int ktg = ro * 8 + kto;
                const ushort* ap = sHi + kto * 1024 + aq;
                const ushort* alp = sLo + kto * 1024 + aq;
                const short8 ah0 = *(const short8*)(ap + xod);
                const short8 ah1 = *(const short8*)(ap + 128 + xod);
                const short8 al0 = *(const short8*)(alp + xod);
                const short8 al1 = *(const short8*)(alp + 128 + xod);
                const short8 bh = *(const short8*)(bph + ktg * 4096);
                const short8 bl = *(const short8*)(bpl + ktg * 4096);
                acc0 = __builtin_amdgcn_mfma_f32_16x16x32_bf16(ah0, bh, acc0, 0, 0, 0);
                acc1 = __builtin_amdgcn_mfma_f32_16x16x32_bf16(ah1, bh, acc1, 0, 0, 0);
                acc0 = __builtin_amdgcn_mfma_f32_16x16x32_bf16(ah0, bl, acc0, 0, 0, 0);
                acc1 = __builtin_amdgcn_mfma_f32_16x16x32_bf16(ah1, bl, acc1, 0, 0, 0);
                acc0 = __builtin_amdgcn_mfma_f32_16x16x32_bf16(al0, bh, acc0, 0, 0, 0);
                acc1 = __builtin_amdgcn_mfma_f32_16x16x32_bf16(al1, bh, acc1, 0, 0, 0);
            }
        }
        if (ro < 3) __syncthreads();  // phase-2 reads done before next round's flush
    }

    // ---- epilogue: bias/relu, store, optional fused gate ----
    const float b0 = bias[n0];
    float gp0[4], gp1[4];
#pragma unroll
    for (int r = 0; r < 4; r++) {
        const int row0 = q2 * 4 + r;            // C/D: row=(lane>>4)*4+reg, col=lane&15
        const int nodeA = blockIdx.x * NBN + row0;
        const int nodeB = nodeA + 16;
        float v0 = acc0[r] + b0;
        float v1 = acc1[r] + b0;
        if (RELU) { v0 = fmaxf(v0, 0.f); v1 = fmaxf(v1, 0.f); }
        if (nodeA < N_NODES) hout[(size_t)nodeA * DIM + n0] = v0;
        if (nodeB < N_NODES) hout[(size_t)nodeB * DIM + n0] = v1;
        if (GATE) { gp0[r] = v0 * gw[n0]; gp1[r] = v1 * gw[n0]; }
    }
    if (GATE) {
#pragma unroll
        for (int r = 0; r < 4; r++) {
#pragma unroll
            for (int s = 1; s < 16; s <<= 1) {
                gp0[r] += __shfl_xor(gp0[r], s, 16);
                gp1[r] += __shfl_xor(gp1[r], s, 16);
            }
        }
        __syncthreads();  // all phase-2 LDS reads done (paranoia; sgatep separate)
        if (mm == 0) {
#pragma unroll
            for (int r = 0; r < 4; r++) {
                sgatep[q2 * 4 + r][w] = gp0[r];
                sgatep[16 + q2 * 4 + r][w] = gp1[r];
            }
        }
        __syncthreads();
        if (tid < NBN) {
            const int n = blockIdx.x * NBN + tid;
            if (n < N_NODES) {
                float s = 0.f;
#pragma unroll
                for (int w8 = 0; w8 < 8; w8++) s += sgatep[tid][w8];
                gate[n] = s + gb[0];
            }
        }
    }
}

// One block (256 threads) per graph: segment softmax + weighted readout + MLP head + sigmoid.
__global__ __launch_bounds__(256) void k_pool(
    const float* __restrict__ h3, const float* __restrict__ gate, const int* __restrict__ n2g,
    const float* __restrict__ fc1w, const float* __restrict__ fc1b,
    const float* __restrict__ fc2w, const float* __restrict__ fc2b,
    const float* __restrict__ fc3w, const float* __restrict__ fc3b,
    float* __restrict__ out, int N) {
    const int g = blockIdx.x;
    const int tid = threadIdx.x;
    __shared__ float sred[256];
    __shared__ float sr[128];
    __shared__ float sz1[100];
    __shared__ float sz2[64];
    __shared__ float sm, ssum;

    const int s = lower_bound_i(n2g, N, g);
    const int e = lower_bound_i(n2g, N, g + 1);

    float m = -3.4e38f;
    for (int n = s + tid; n < e; n += 256) m = fmaxf(m, gate[n]);
    sred[tid] = m;
    __syncthreads();
    for (int off = 128; off > 0; off >>= 1) {
        if (tid < off) sred[tid] = fmaxf(sred[tid], sred[tid + off]);
        __syncthreads();
    }
    if (tid == 0) sm = sred[0];
    __syncthreads();
    const float mm = sm;

    float sum = 0.f;
    for (int n = s + tid; n < e; n += 256) sum += expf(gate[n] - mm);
    sred[tid] = sum;
    __syncthreads();
    for (int off = 128; off > 0; off >>= 1) {
        if (tid < off) sred[tid] += sred[tid + off];
        __syncthreads();
    }
    if (tid == 0) ssum = sred[0];
    __syncthreads();
    const float inv = (e > s) ? 1.0f / ssum : 0.f;

    // weighted readout: col = tid&127, node stream split across two halves,
    // unrolled x4 per half (8 loads in flight across the block)
    const int col = tid & 127;
    const int half = tid >> 7;
    float acc = 0.f;
    int n = s + half;
    for (; n + 6 < e; n += 8) {
        const float w0 = expf(gate[n] - mm);
        const float w1 = expf(gate[n + 2] - mm);
        const float w2 = expf(gate[n + 4] - mm);
        const float w3 = expf(gate[n + 6] - mm);
        const float a0 = h3[(size_t)n * DIM + col];
        const float a1 = h3[(size_t)(n + 2) * DIM + col];
        const float a2 = h3[(size_t)(n + 4) * DIM + col];
        const float a3 = h3[(size_t)(n + 6) * DIM + col];
        acc = fmaf(w0, a0, acc);
        acc = fmaf(w1, a1, acc);
        acc = fmaf(w2, a2, acc);
        acc = fmaf(w3, a3, acc);
    }
    for (; n < e; n += 2) {
        const float wgt = expf(gate[n] - mm);
        acc = fmaf(wgt, h3[(size_t)n * DIM + col], acc);
    }
    sred[tid] = acc;
    __syncthreads();
    if (tid < 128) sr[tid] = (sred[tid] + sred[tid + 128]) * inv;
    __syncthreads();

    if (tid < 100) {
        float t = fc1b[tid];
        for (int i = 0; i < 128; i++) t = fmaf(sr[i], fc1w[i * 100 + tid], t);
        sz1[tid] = fmaxf(t, 0.f);
    }
    __syncthreads();
    if (tid < 64) {
        float t = fc2b[tid];
        for (int i = 0; i < 100; i++) t = fmaf(sz1[i], fc2w[i * 64 + tid], t);
        sz2[tid] = fmaxf(t, 0.f);
    }
    __syncthreads();
    if (tid < 64) {
        float p = sz2[tid] * fc3w[tid];
#pragma unroll
        for (int off = 32; off > 0; off >>= 1) p += __shfl_down(p, off, 64);
        if (tid == 0) {
            const float z = p + fc3b[0];
            out[g] = 1.0f / (1.0f + expf(-z));
        }
    }
}

extern "C" void kernel_launch(void* const* d_in, const int* in_sizes, int n_in,
                              void* d_out, int out_size, void* d_ws, size_t ws_size,
                              hipStream_t stream) {
    (void)in_sizes; (void)n_in; (void)out_size; (void)ws_size;
    const float* features = (const float*)d_in[0];
    const int*   src      = (const int*)d_in[1];
    const int*   dst      = (const int*)d_in[2];
    const int*   etype    = (const int*)d_in[3];
    const int*   n2g      = (const int*)d_in[4];
    const float* bases1   = (const float*)d_in[5];
    const float* comp1    = (const float*)d_in[6];
    const float* bias1    = (const float*)d_in[7];
    const float* bases2   = (const float*)d_in[8];
    const float* comp2    = (const float*)d_in[9];
    const float* bias2    = (const float*)d_in[10];
    const float* bases3   = (const float*)d_in[11];
    const float* comp3    = (const float*)d_in[12];
    const float* bias3    = (const float*)d_in[13];
    const float* gate_w   = (const float*)d_in[14];
    const float* gate_b   = (const float*)d_in[15];
    const float* fc1w     = (const float*)d_in[16];
    const float* fc1b     = (const float*)d_in[17];
    const float* fc2w     = (const float*)d_in[18];
    const float* fc2b     = (const float*)d_in[19];
    const float* fc3w     = (const float*)d_in[20];
    const float* fc3b     = (const float*)d_in[21];
    float* out = (float*)d_out;

    char* w = (char*)d_ws;
    auto alloc = [&](size_t bytes) -> char* {
        char* p = w;
        w += (bytes + 255) & ~(size_t)255;
        return p;
    };
    int*    counts  = (int*)alloc((NKEY2 + 64) * sizeof(int));            // 0.8 MB
    int*    edges   = (int*)alloc(((size_t)NKEY2 * CAP + 64) * sizeof(int));  // 25.6 MB
    float*  hA      = (float*)alloc((size_t)N_NODES * DIM * sizeof(float));
    float*  hB      = (float*)alloc((size_t)N_NODES * DIM * sizeof(float));
    float*  gate    = (float*)alloc(N_NODES * sizeof(float));
    ushort* Whi1    = (ushort*)alloc((size_t)KDIM * DIM * sizeof(ushort));
    ushort* Wlo1    = (ushort*)alloc((size_t)KDIM * DIM * sizeof(ushort));
    ushort* Whi2    = (ushort*)alloc((size_t)KDIM * DIM * sizeof(ushort));
    ushort* Wlo2    = (ushort*)alloc((size_t)KDIM * DIM * sizeof(ushort));
    ushort* Whi3    = (ushort*)alloc((size_t)KDIM * DIM * sizeof(ushort));
    ushort* Wlo3    = (ushort*)alloc((size_t)KDIM * DIM * sizeof(ushort));

    // weight packing (+ counts zeroing, ordered before k_fill on the stream)
    k_packW3<<<1536, 256, 0, stream>>>(bases1, comp1, Whi1, Wlo1,
                                       bases2, comp2, Whi2, Wlo2,
                                       bases3, comp3, Whi3, Wlo3, counts);

    // CAP-bucket CSR (rebuilt every call): fill only (no memset/count/scan)
    k_fill<<<(N_EDGES + 255) / 256, 256, 0, stream>>>(src, dst, etype, counts, edges, N_EDGES);

    // 3 RGCN layers (bucketed aggregation + 4-round K-quartered MFMA GEMM)
    k_layer<true, false><<<NBLK, 512, 0, stream>>>(features, hA, edges, counts, Whi1, Wlo1, bias1, gate_w, gate_b, gate);
    k_layer<true, false><<<NBLK, 512, 0, stream>>>(hA, hB, edges, counts, Whi2, Wlo2, bias2, gate_w, gate_b, gate);
    k_layer<false, true><<<NBLK, 512, 0, stream>>>(hB, hA, edges, counts, Whi3, Wlo3, bias3, gate_w, gate_b, gate);

    // pooling + MLP head (gate computed in layer 3)
    k_pool<<<N_GRAPHS, 256, 0, stream>>>(hA, gate, n2g, fc1w, fc1b, fc2w, fc2b, fc3w, fc3b, out, N_NODES);
}